// Round 1
// baseline (621.099 us; speedup 1.0000x reference)
//
#include <hip/hip_runtime.h>

#define NWIN 49
#define CDIM 128
#define SCALEQ 0.17677669529663687f

typedef _Float16 half8 __attribute__((ext_vector_type(8)));
typedef _Float16 half4v __attribute__((ext_vector_type(4)));
typedef _Float16 half2v __attribute__((ext_vector_type(2)));
typedef float f32x4 __attribute__((ext_vector_type(4)));

// LDS layout (bytes). Region1 = x (GEMM1 A) overlaid with P (per-wave) and O.
// Region2 = per-wave Q,K,V^T. All strides chosen 16B-aligned, <=2-way bank alias.
#define XL_STR 136   // halves, x tile stride (272 B)
#define P_STR  72    // halves (144 B)
#define QK_STR 40    // halves (80 B)
#define VT_STR 72    // halves (144 B)
#define OL_STR 136   // halves (272 B)
#define P_SZB    (49 * P_STR * 2)        // 7056
#define REG1_SZB (4 * P_SZB)             // 28224
#define QW_SZB   (49 * QK_STR * 2)       // 3920
#define VT_SZB   (32 * VT_STR * 2)       // 4608
#define WAVE2_SZB (2 * QW_SZB + VT_SZB)  // 12448
#define SMEM_SZB (REG1_SZB + 4 * WAVE2_SZB) // 78016 -> 2 blocks/CU

__global__ __launch_bounds__(256, 2)
void lwa_fused(const float* __restrict__ x,
               const float* __restrict__ w_qkv,
               const float* __restrict__ b_qkv,
               const float* __restrict__ w_proj,
               const float* __restrict__ b_proj,
               const float* __restrict__ bias_table,
               const int* __restrict__ rel_index,
               float* __restrict__ out,
               int nwin_total, int wpb)
{
    __shared__ __align__(16) char smem[SMEM_SZB];
    const int tid  = threadIdx.x;
    const int w    = tid >> 6;       // wave = head
    const int lane = tid & 63;
    const int lo   = lane & 15;
    const int hi   = lane >> 4;

    _Float16* const xl  = (_Float16*)smem;                                // region1
    _Float16* const Ol  = (_Float16*)smem;                                // region1 (diff phase)
    _Float16* const Pw  = (_Float16*)(smem + w * P_SZB);                  // region1 (diff phase)
    _Float16* const Qw  = (_Float16*)(smem + REG1_SZB + w * WAVE2_SZB);
    _Float16* const Kw  = Qw + 49 * QK_STR;
    _Float16* const VTw = (_Float16*)(smem + REG1_SZB + w * WAVE2_SZB + 2 * QW_SZB);

    // ---------- per-block setup: weight B-fragments + bias into registers ----------
    // GEMM1 B-frag: B[k][n] = w_qkv[n][k]; lane holds col n = base+lo, k = kk*32+hi*8+j
    half8 wb1[6][4];
    float bq[6];
#pragma unroll
    for (int tn = 0; tn < 6; ++tn) {
        int base = (tn < 2) ? (w * 32 + tn * 16)
                 : (tn < 4) ? (128 + w * 32 + (tn - 2) * 16)
                            : (256 + w * 32 + (tn - 4) * 16);
        int n = base + lo;
        bq[tn] = b_qkv[n];
#pragma unroll
        for (int kk = 0; kk < 4; ++kk) {
            const float* p = w_qkv + (size_t)n * CDIM + kk * 32 + hi * 8;
            float4 u0 = *reinterpret_cast<const float4*>(p);
            float4 u1 = *reinterpret_cast<const float4*>(p + 4);
            half8 h;
            h[0] = (_Float16)u0.x; h[1] = (_Float16)u0.y; h[2] = (_Float16)u0.z; h[3] = (_Float16)u0.w;
            h[4] = (_Float16)u1.x; h[5] = (_Float16)u1.y; h[6] = (_Float16)u1.z; h[7] = (_Float16)u1.w;
            wb1[tn][kk] = h;
        }
    }
    half8 wb3[2][4];
    float bp[2];
#pragma unroll
    for (int tn = 0; tn < 2; ++tn) {
        int n = w * 32 + tn * 16 + lo;
        bp[tn] = b_proj[n];
#pragma unroll
        for (int kk = 0; kk < 4; ++kk) {
            const float* p = w_proj + (size_t)n * CDIM + kk * 32 + hi * 8;
            float4 u0 = *reinterpret_cast<const float4*>(p);
            float4 u1 = *reinterpret_cast<const float4*>(p + 4);
            half8 h;
            h[0] = (_Float16)u0.x; h[1] = (_Float16)u0.y; h[2] = (_Float16)u0.z; h[3] = (_Float16)u0.w;
            h[4] = (_Float16)u1.x; h[5] = (_Float16)u1.y; h[6] = (_Float16)u1.z; h[7] = (_Float16)u1.w;
            wb3[tn][kk] = h;
        }
    }
    // relative-position bias, fixed per lane: S element (tm,tn,j) is (q = 16tm+4hi+j, key = 16tn+lo)
    // key >= 49 masked with -1e4 (exp -> 0). q >= 49 rows are don't-care (clamped gather).
    half2v biasp[4][4][2];
#pragma unroll
    for (int tm = 0; tm < 4; ++tm)
#pragma unroll
        for (int tn = 0; tn < 4; ++tn)
#pragma unroll
            for (int jp = 0; jp < 2; ++jp) {
                float bv[2];
#pragma unroll
                for (int j2 = 0; j2 < 2; ++j2) {
                    int j = jp * 2 + j2;
                    int q = 16 * tm + 4 * hi + j;
                    int key = 16 * tn + lo;
                    if (key >= 49) bv[j2] = -1e4f;
                    else {
                        int qc = (q < 49) ? q : 48;
                        bv[j2] = bias_table[(size_t)rel_index[qc * 49 + key] * 4 + w];
                    }
                }
                half2v h; h[0] = (_Float16)bv[0]; h[1] = (_Float16)bv[1];
                biasp[tm][tn][jp] = h;
            }

    const f32x4 zf = {0.f, 0.f, 0.f, 0.f};

    // ---------- window loop ----------
    int b0 = blockIdx.x * wpb;
    int b1 = b0 + wpb; if (b1 > nwin_total) b1 = nwin_total;
    for (int b = b0; b < b1; ++b) {
        // Phase A: stage x[b] (49x128 f32) -> LDS f16, padded stride
        {
            int r = tid >> 4;
            int gcol = (tid & 15) * 8;
#pragma unroll
            for (int p = 0; p < 4; ++p) {
                int row = r + p * 16;
                if (row < 49) {
                    const float* src = x + ((size_t)b * NWIN + row) * CDIM + gcol;
                    float4 u0 = *reinterpret_cast<const float4*>(src);
                    float4 u1 = *reinterpret_cast<const float4*>(src + 4);
                    half8 h;
                    h[0] = (_Float16)u0.x; h[1] = (_Float16)u0.y; h[2] = (_Float16)u0.z; h[3] = (_Float16)u0.w;
                    h[4] = (_Float16)u1.x; h[5] = (_Float16)u1.y; h[6] = (_Float16)u1.z; h[7] = (_Float16)u1.w;
                    *reinterpret_cast<half8*>(&xl[row * XL_STR + gcol]) = h;
                }
            }
        }
        __syncthreads(); // 1: x staged

        // Phase B: qkv = x @ w_qkv^T (+b). Wave w computes its head's q,k,v slices.
        // Epilogue scatters to Qw (scaled), Kw, and V transposed into VTw (all 64 token
        // rows written for V so MFMA K-padding reads finite values).
#pragma unroll
        for (int tm = 0; tm < 4; ++tm) {
            int ar = 16 * tm + lo; if (ar > 48) ar = 48;
            half8 a[4];
#pragma unroll
            for (int kk = 0; kk < 4; ++kk)
                a[kk] = *reinterpret_cast<const half8*>(&xl[ar * XL_STR + kk * 32 + hi * 8]);
            f32x4 acc[6];
#pragma unroll
            for (int tn = 0; tn < 6; ++tn) acc[tn] = zf;
#pragma unroll
            for (int tn = 0; tn < 6; ++tn)
#pragma unroll
                for (int kk = 0; kk < 4; ++kk)
                    acc[tn] = __builtin_amdgcn_mfma_f32_16x16x32_f16(a[kk], wb1[tn][kk], acc[tn], 0, 0, 0);
#pragma unroll
            for (int tn = 0; tn < 6; ++tn) {
                if (tn < 4) {
#pragma unroll
                    for (int j = 0; j < 4; ++j) {
                        int row = 16 * tm + 4 * hi + j;
                        if (row < 49) {
                            float v = acc[tn][j] + bq[tn];
                            if (tn < 2) Qw[row * QK_STR + tn * 16 + lo] = (_Float16)(v * SCALEQ);
                            else        Kw[row * QK_STR + (tn - 2) * 16 + lo] = (_Float16)v;
                        }
                    }
                } else {
                    half4v hv;
#pragma unroll
                    for (int j = 0; j < 4; ++j) hv[j] = (_Float16)(acc[tn][j] + bq[tn]);
                    *reinterpret_cast<half4v*>(&VTw[((tn - 4) * 16 + lo) * VT_STR + tm * 16 + 4 * hi]) = hv;
                }
            }
        }
        __syncthreads(); // 2: x dead -> P region writable

        // Phase C: S = Q K^T (+bias), wave-parallel softmax, P -> LDS (f16), deferred 1/l
        float inv_l[4][4];
        {
            half8 kf[4];
#pragma unroll
            for (int tn = 0; tn < 4; ++tn) {
                int kr = 16 * tn + lo; if (kr > 48) kr = 48;
                kf[tn] = *reinterpret_cast<const half8*>(&Kw[kr * QK_STR + hi * 8]);
            }
#pragma unroll
            for (int tm = 0; tm < 4; ++tm) {
                int qr = 16 * tm + lo; if (qr > 48) qr = 48;
                half8 qf = *reinterpret_cast<const half8*>(&Qw[qr * QK_STR + hi * 8]);
                f32x4 s[4];
#pragma unroll
                for (int tn = 0; tn < 4; ++tn)
                    s[tn] = __builtin_amdgcn_mfma_f32_16x16x32_f16(qf, kf[tn], zf, 0, 0, 0);
#pragma unroll
                for (int tn = 0; tn < 4; ++tn)
#pragma unroll
                    for (int jp = 0; jp < 2; ++jp) {
                        s[tn][2 * jp]     += (float)biasp[tm][tn][jp][0];
                        s[tn][2 * jp + 1] += (float)biasp[tm][tn][jp][1];
                    }
#pragma unroll
                for (int j = 0; j < 4; ++j) {
                    float m = fmaxf(fmaxf(s[0][j], s[1][j]), fmaxf(s[2][j], s[3][j]));
                    m = fmaxf(m, __shfl_xor(m, 1));
                    m = fmaxf(m, __shfl_xor(m, 2));
                    m = fmaxf(m, __shfl_xor(m, 4));
                    m = fmaxf(m, __shfl_xor(m, 8));
                    float sum = 0.f;
#pragma unroll
                    for (int tn = 0; tn < 4; ++tn) {
                        float p = __expf(s[tn][j] - m);
                        s[tn][j] = p;
                        sum += p;
                    }
                    sum += __shfl_xor(sum, 1);
                    sum += __shfl_xor(sum, 2);
                    sum += __shfl_xor(sum, 4);
                    sum += __shfl_xor(sum, 8);
                    inv_l[tm][j] = 1.0f / sum;
                }
#pragma unroll
                for (int tn = 0; tn < 4; ++tn)
#pragma unroll
                    for (int j = 0; j < 4; ++j) {
                        int q = 16 * tm + 4 * hi + j;
                        if (q < 49) Pw[q * P_STR + tn * 16 + lo] = (_Float16)s[tn][j];
                    }
            }
        }

        // Phase D: O_h = P @ V (keys padded to 64; P cols >=49 are exp(-1e4)=0)
        f32x4 o[4][2];
#pragma unroll
        for (int tm = 0; tm < 4; ++tm)
#pragma unroll
            for (int t2 = 0; t2 < 2; ++t2) o[tm][t2] = zf;
        {
            half8 vf[2][2];
#pragma unroll
            for (int t2 = 0; t2 < 2; ++t2)
#pragma unroll
                for (int kk2 = 0; kk2 < 2; ++kk2)
                    vf[t2][kk2] = *reinterpret_cast<const half8*>(&VTw[(t2 * 16 + lo) * VT_STR + kk2 * 32 + hi * 8]);
#pragma unroll
            for (int tm = 0; tm < 4; ++tm) {
                int pr = 16 * tm + lo; if (pr > 48) pr = 48;
                half8 pf[2];
#pragma unroll
                for (int kk2 = 0; kk2 < 2; ++kk2)
                    pf[kk2] = *reinterpret_cast<const half8*>(&Pw[pr * P_STR + kk2 * 32 + hi * 8]);
#pragma unroll
                for (int t2 = 0; t2 < 2; ++t2)
#pragma unroll
                    for (int kk2 = 0; kk2 < 2; ++kk2)
                        o[tm][t2] = __builtin_amdgcn_mfma_f32_16x16x32_f16(pf[kk2], vf[t2][kk2], o[tm][t2], 0, 0, 0);
            }
        }
        __syncthreads(); // 3: all P/VT reads done -> region1 writable as O
#pragma unroll
        for (int tm = 0; tm < 4; ++tm)
#pragma unroll
            for (int t2 = 0; t2 < 2; ++t2)
#pragma unroll
                for (int j = 0; j < 4; ++j) {
                    int row = 16 * tm + 4 * hi + j;
                    if (row < 49)
                        Ol[row * OL_STR + w * 32 + t2 * 16 + lo] = (_Float16)(o[tm][t2][j] * inv_l[tm][j]);
                }
        __syncthreads(); // 4: O complete

        // Phase E: out = O @ w_proj^T + b_proj, f32 coalesced store
#pragma unroll
        for (int tm = 0; tm < 4; ++tm) {
            int orr = 16 * tm + lo; if (orr > 48) orr = 48;
            half8 oa[4];
#pragma unroll
            for (int kk = 0; kk < 4; ++kk)
                oa[kk] = *reinterpret_cast<const half8*>(&Ol[orr * OL_STR + kk * 32 + hi * 8]);
            f32x4 g[2];
#pragma unroll
            for (int tn = 0; tn < 2; ++tn) g[tn] = zf;
#pragma unroll
            for (int tn = 0; tn < 2; ++tn)
#pragma unroll
                for (int kk = 0; kk < 4; ++kk)
                    g[tn] = __builtin_amdgcn_mfma_f32_16x16x32_f16(oa[kk], wb3[tn][kk], g[tn], 0, 0, 0);
#pragma unroll
            for (int tn = 0; tn < 2; ++tn)
#pragma unroll
                for (int j = 0; j < 4; ++j) {
                    int row = 16 * tm + 4 * hi + j;
                    if (row < 49)
                        out[((size_t)b * NWIN + row) * CDIM + w * 32 + tn * 16 + lo] = g[tn][j] + bp[tn];
                }
        }
        __syncthreads(); // 5: O reads done -> next window may restage x
    }
}

extern "C" void kernel_launch(void* const* d_in, const int* in_sizes, int n_in,
                              void* d_out, int out_size, void* d_ws, size_t ws_size,
                              hipStream_t stream) {
    const float* x          = (const float*)d_in[0];
    // d_in[1] = q_global: unused by the reference
    const float* w_qkv      = (const float*)d_in[2];
    const float* b_qkv      = (const float*)d_in[3];
    const float* w_proj     = (const float*)d_in[4];
    const float* b_proj     = (const float*)d_in[5];
    const float* bias_table = (const float*)d_in[6];
    const int*   rel_index  = (const int*)d_in[7];

    const int nwin = in_sizes[0] / (NWIN * CDIM);   // 16384
    const int wpb = 8;
    const int nblk = (nwin + wpb - 1) / wpb;        // 2048

    lwa_fused<<<nblk, 256, 0, stream>>>(x, w_qkv, b_qkv, w_proj, b_proj,
                                        bias_table, rel_index, (float*)d_out,
                                        nwin, wpb);
}